// Round 3
// baseline (141.351 us; speedup 1.0000x reference)
//
#include <hip/hip_runtime.h>
#include <hip/hip_bf16.h>
#include <stdint.h>

#define BATCH 32
#define SEQT  1024
#define INF   1024
#define OUTF  512
#define MROWS (BATCH * SEQT)   // 32768

typedef __attribute__((ext_vector_type(8))) short short8;
typedef __attribute__((ext_vector_type(4))) float f32x4;

__device__ __forceinline__ short f2bf(float f) {
    return (short)__builtin_bit_cast(unsigned short, __float2bfloat16(f));
}

// Pair-packed swizzled LDS offset (shorts) for a 128x32 bf16 tile.
// Two rows share one 128B line; slot = (g | parity<<2) ^ (line&7).
// Verified 2-way (free) on both ds_write_b128 and ds_read_b128 sides.
__device__ __forceinline__ int swz(int row, int g) {
    const int line = row >> 1;
    const int slot = (g | ((row & 1) << 2)) ^ (line & 7);
    return (line << 6) + (slot << 3);
}

// ---------------------------------------------------------------------------
// GEMM: cur[m,o] = bf16( sum_k X[m,k]*W[o,k] + bias[o] )
// 128x128 tile, BK=32, 256 threads (2x2 waves of 64x64).
// LDS double-buffered (2 x 16 KB) -> 34.8 KB total -> 4 blocks/CU (16 waves)
// for TLP latency hiding; 1-deep reg prefetch; single barrier per K-step.
// ---------------------------------------------------------------------------
__global__ __launch_bounds__(256, 4) void gemm_bf16_kernel(
    const float* __restrict__ X, const float* __restrict__ W,
    const float* __restrict__ bias, __hip_bfloat16* __restrict__ C) {
    // K-loop view: 2 bufs x 2 mats x 4096 shorts (32 KB).
    // Epilogue view: 128 x 136 shorts (34.8 KB). Union-sized.
    __shared__ short lds[17408];

    const int tid = threadIdx.x;
    const int bid = blockIdx.x;
    // XCD-chunked, mt-major: xcd owns 32 m-tiles x 4 n-tiles; A panel fetched
    // once into its L2. Bijective over 1024 blocks.
    const int xcd = bid & 7;
    const int idx = bid >> 3;
    const int mt  = (xcd << 5) + (idx >> 2);
    const int nt  = idx & 3;
    const int m0 = mt << 7;
    const int o0 = nt << 7;

    const int wv   = tid >> 6;
    const int lane = tid & 63;
    const int wr = wv >> 1;
    const int wc = wv & 1;
    const int r0 = lane & 15;
    const int lg = lane >> 4;

    // staging coords: idx2 = it*256+tid covers 128 rows x 4 granules (8 f32)
    const float* pa[2];
    const float* pb[2];
    int srow[2], skg[2];
#pragma unroll
    for (int it = 0; it < 2; ++it) {
        const int idx2 = (it << 8) + tid;
        srow[it] = idx2 >> 2;
        skg[it]  = idx2 & 3;
        pa[it] = X + (size_t)(m0 + srow[it]) * INF + (skg[it] << 3);
        pb[it] = W + (size_t)(o0 + srow[it]) * INF + (skg[it] << 3);
    }

    f32x4 rA[2][2], rB[2][2];
#pragma unroll
    for (int it = 0; it < 2; ++it) {
        rA[it][0] = *(const f32x4*)(pa[it]);
        rA[it][1] = *(const f32x4*)(pa[it] + 4);
        rB[it][0] = *(const f32x4*)(pb[it]);
        rB[it][1] = *(const f32x4*)(pb[it] + 4);
    }

    f32x4 acc[4][4] = {};

    for (int kt = 0; kt < 32; ++kt) {
        short* la = &lds[(kt & 1) << 13];
        short* lb = la + 4096;
        // ---- cvt staged regs -> LDS (swizzled write) ----
#pragma unroll
        for (int it = 0; it < 2; ++it) {
            const int off = swz(srow[it], skg[it]);
            short8 ha, hb;
#pragma unroll
            for (int j = 0; j < 4; ++j) {
                ha[j] = f2bf(rA[it][0][j]); ha[4 + j] = f2bf(rA[it][1][j]);
                hb[j] = f2bf(rB[it][0][j]); hb[4 + j] = f2bf(rB[it][1][j]);
            }
            *(short8*)&la[off] = ha;
            *(short8*)&lb[off] = hb;
        }
        // ---- issue next K-step's global loads ----
        if (kt < 31) {
            const int kb = (kt + 1) << 5;
#pragma unroll
            for (int it = 0; it < 2; ++it) {
                rA[it][0] = *(const f32x4*)(pa[it] + kb);
                rA[it][1] = *(const f32x4*)(pa[it] + kb + 4);
                rB[it][0] = *(const f32x4*)(pb[it] + kb);
                rB[it][1] = *(const f32x4*)(pb[it] + kb + 4);
            }
        }
        __syncthreads();   // single barrier per K-step (dbuf makes it safe)
        // ---- compute: one k-step of 32, 4x4 fragments per wave ----
        short8 av[4], bv[4];
#pragma unroll
        for (int mi = 0; mi < 4; ++mi) {
            const int row = (wr << 6) + (mi << 4) + r0;
            av[mi] = *(const short8*)&la[swz(row, lg)];
        }
#pragma unroll
        for (int ni = 0; ni < 4; ++ni) {
            const int row = (wc << 6) + (ni << 4) + r0;
            bv[ni] = *(const short8*)&lb[swz(row, lg)];
        }
#pragma unroll
        for (int mi = 0; mi < 4; ++mi)
#pragma unroll
            for (int ni = 0; ni < 4; ++ni)
                acc[mi][ni] = __builtin_amdgcn_mfma_f32_16x16x32_bf16(
                    av[mi], bv[ni], acc[mi][ni], 0, 0, 0);
    }

    // ---- epilogue: acc -> LDS (stride 136 shorts) -> coalesced bf16 stores
    __syncthreads();
    short* cs = &lds[0];
#pragma unroll
    for (int ni = 0; ni < 4; ++ni) {
        const int col = (wc << 6) + (ni << 4) + r0;
        const float bb = bias[o0 + col];
#pragma unroll
        for (int mi = 0; mi < 4; ++mi) {
            const int rb = (wr << 6) + (mi << 4) + (lg << 2);
#pragma unroll
            for (int j = 0; j < 4; ++j)
                cs[(rb + j) * 136 + col] = f2bf(acc[mi][ni][j] + bb);
        }
    }
    __syncthreads();
    const int r16 = tid >> 4, c16 = tid & 15;
    short* cg = (short*)C;
#pragma unroll
    for (int p = 0; p < 8; ++p) {
        const int row = (p << 4) + r16;
        short8 v = *(const short8*)&cs[row * 136 + (c16 << 3)];
        *(short8*)&cg[(size_t)(m0 + row) * OUTF + o0 + (c16 << 3)] = v;
    }
}

// ---------------------------------------------------------------------------
// Scan: u_t = d*u_{t-1} + (1-d)*c_t, segmented (8 segs of 128) with 128-step
// warm-up (d^128 ~ 1.7e-3). cur is bf16. One thread per (b, seg, o).
// ---------------------------------------------------------------------------
template <bool WRITE_OUT>
__global__ __launch_bounds__(256) void scan_kernel(
    const __hip_bfloat16* __restrict__ cur, float* __restrict__ outp,
    float* __restrict__ states, const float* __restrict__ decay) {
    const int gid = blockIdx.x * 256 + threadIdx.x;
    const int o   = gid & 511;
    const int seg = (gid >> 9) & 7;
    const int b   = gid >> 12;

    const float d   = decay[o];
    const float omd = 1.0f - d;
    const __hip_bfloat16* c = cur + (size_t)b * (SEQT * OUTF) + o;
    float* sp = states + (size_t)b * ((SEQT + 1) * OUTF) + o;

    if (seg == 0) sp[0] = 0.0f;

    float u = 0.0f;
    const int t0 = seg << 7;
    const int tw = (seg == 0) ? 0 : (t0 - 128);
    for (int t = tw; t < t0; t += 8) {   // warm-up (no stores)
        float r[8];
#pragma unroll
        for (int j = 0; j < 8; ++j) r[j] = __bfloat162float(c[(size_t)(t + j) * OUTF]);
#pragma unroll
        for (int j = 0; j < 8; ++j) u = fmaf(d, u, omd * r[j]);
    }
    float* op = outp + (size_t)b * (SEQT * OUTF) + o;
    for (int t = t0; t < t0 + 128; t += 8) {
        float r[8];
#pragma unroll
        for (int j = 0; j < 8; ++j) r[j] = __bfloat162float(c[(size_t)(t + j) * OUTF]);
        float uu[8];
#pragma unroll
        for (int j = 0; j < 8; ++j) { u = fmaf(d, u, omd * r[j]); uu[j] = u; }
#pragma unroll
        for (int j = 0; j < 8; ++j) sp[(size_t)(t + 1 + j) * OUTF] = uu[j];
        if (WRITE_OUT) {
#pragma unroll
            for (int j = 0; j < 8; ++j) op[(size_t)(t + j) * OUTF] = uu[j];
        }
    }
}

// outputs[b,t,o] = states[b,t+1,o]  (fallback path only)
__global__ __launch_bounds__(256) void copy_out_kernel(
    float* __restrict__ outp, const float* __restrict__ states) {
    const size_t total = (size_t)MROWS * OUTF / 4;
    size_t i = (size_t)blockIdx.x * blockDim.x + threadIdx.x;
    const size_t stride = (size_t)gridDim.x * blockDim.x;
    for (; i < total; i += stride) {
        const size_t flat = i * 4;
        const size_t o  = flat & 511;
        const size_t bt = flat >> 9;
        const size_t b  = bt >> 10;
        const size_t t  = bt & 1023;
        *(f32x4*)&outp[flat] =
            *(const f32x4*)&states[(b * (SEQT + 1) + t + 1) * OUTF + o];
    }
}

extern "C" void kernel_launch(void* const* d_in, const int* in_sizes, int n_in,
                              void* d_out, int out_size, void* d_ws, size_t ws_size,
                              hipStream_t stream) {
    const float* x     = (const float*)d_in[0];
    const float* w     = (const float*)d_in[1];
    const float* bias  = (const float*)d_in[2];
    const float* decay = (const float*)d_in[3];

    float* outp   = (float*)d_out;
    float* states = outp + (size_t)MROWS * OUTF;   // [B, T+1, OUT] flat

    const size_t cur_bytes = (size_t)MROWS * OUTF * sizeof(__hip_bfloat16);  // 32 MB
    const bool use_ws = (ws_size >= cur_bytes);
    __hip_bfloat16* cur = use_ws ? (__hip_bfloat16*)d_ws : (__hip_bfloat16*)outp;

    gemm_bf16_kernel<<<dim3(1024), dim3(256), 0, stream>>>(x, w, bias, cur);

    if (use_ws) {
        scan_kernel<true><<<dim3(512), dim3(256), 0, stream>>>(cur, outp, states, decay);
    } else {
        scan_kernel<false><<<dim3(512), dim3(256), 0, stream>>>(cur, nullptr, states, decay);
        copy_out_kernel<<<dim3(2048), dim3(256), 0, stream>>>(outp, states);
    }
}

// Round 4
// 111.166 us; speedup vs baseline: 1.2715x; 1.2715x over previous
//
#include <hip/hip_runtime.h>
#include <hip/hip_bf16.h>
#include <stdint.h>

#define BATCH 32
#define SEQT  1024
#define INF   1024
#define OUTF  512
#define MROWS (BATCH * SEQT)   // 32768

typedef __attribute__((ext_vector_type(8))) short short8;
typedef __attribute__((ext_vector_type(4))) float f32x4;

__device__ __forceinline__ short f2bf(float f) {
    return (short)__builtin_bit_cast(unsigned short, __float2bfloat16(f));
}

// ---------------------------------------------------------------------------
// GEMM: cur[m,o] = bf16( sum_k X[m,k]*W[o,k] + bias[o] )
// 128x128 tile, BK=64, 256 threads (2x2 waves of 64x64).
// Asymmetric-depth reg prefetch: A(X, HBM) 2-deep via P/Q alternating sets
// (kt unrolled by 2 -> all indices static); B(W, L2-resident) 1-deep.
// Issue order B-then-A keeps steady-state wait at vmcnt(8), never 0.
// LDS double-buffered, ONE barrier per K-step, XOR-swizzled (T2 both sides).
// ---------------------------------------------------------------------------
__global__ __launch_bounds__(256, 2) void gemm_bf16_kernel(
    const float* __restrict__ X, const float* __restrict__ W,
    const float* __restrict__ bias, __hip_bfloat16* __restrict__ C) {
    __shared__ short lds[2][2][128 * 64];   // [buf][A/B] : 64 KB

    const int tid = threadIdx.x;
    const int bid = blockIdx.x;
    // XCD-chunked, mt-major: each XCD owns 32 m-tiles x 4 n-tiles; A panel
    // fetched once into its L2, whole W (2 MB fp32) L2-resident. Bijective.
    const int xcd = bid & 7;
    const int idx = bid >> 3;
    const int mt  = (xcd << 5) + (idx >> 2);
    const int nt  = idx & 3;
    const int m0 = mt << 7;
    const int o0 = nt << 7;

    const int wv   = tid >> 6;
    const int lane = tid & 63;
    const int wr = wv >> 1;
    const int wc = wv & 1;
    const int r0 = lane & 15;
    const int lg = lane >> 4;

    // staging coords: idx2 = it*256+tid covers 128 rows x 8 granules of 8 f32
    const float* pa[4];
    const float* pb[4];
    int srow[4], skg[4];
#pragma unroll
    for (int it = 0; it < 4; ++it) {
        const int idx2 = (it << 8) + tid;
        srow[it] = idx2 >> 3;
        skg[it]  = idx2 & 7;
        pa[it] = X + (size_t)(m0 + srow[it]) * INF + (skg[it] << 3);
        pb[it] = W + (size_t)(o0 + srow[it]) * INF + (skg[it] << 3);
    }

    f32x4 PA[4][2], QA[4][2], RB[4][2];
    // prologue issue order: PA(tile0), RB(tile0), QA(tile1)
#pragma unroll
    for (int it = 0; it < 4; ++it) {
        PA[it][0] = *(const f32x4*)(pa[it]);
        PA[it][1] = *(const f32x4*)(pa[it] + 4);
    }
#pragma unroll
    for (int it = 0; it < 4; ++it) {
        RB[it][0] = *(const f32x4*)(pb[it]);
        RB[it][1] = *(const f32x4*)(pb[it] + 4);
    }
#pragma unroll
    for (int it = 0; it < 4; ++it) {
        QA[it][0] = *(const f32x4*)(pa[it] + 64);
        QA[it][1] = *(const f32x4*)(pa[it] + 64 + 4);
    }

    f32x4 acc[4][4] = {};

#define GEMM_PHASE(AREG, BUF, KT)                                            \
    {                                                                        \
        short* la = &lds[BUF][0][0];                                         \
        short* lb = &lds[BUF][1][0];                                         \
        _Pragma("unroll")                                                    \
        for (int it = 0; it < 4; ++it) {                                     \
            const int row = srow[it];                                        \
            const int sw  = (skg[it] ^ (row & 7)) << 3;                      \
            short8 ha, hb;                                                   \
            _Pragma("unroll")                                                \
            for (int j = 0; j < 4; ++j) {                                    \
                ha[j] = f2bf(AREG[it][0][j]); ha[4 + j] = f2bf(AREG[it][1][j]); \
                hb[j] = f2bf(RB[it][0][j]);   hb[4 + j] = f2bf(RB[it][1][j]);   \
            }                                                                \
            *(short8*)&la[(row << 6) + sw] = ha;                             \
            *(short8*)&lb[(row << 6) + sw] = hb;                             \
        }                                                                    \
        if ((KT) + 1 < 16) {   /* B for kt+1 (L2-hit, 1-deep) */             \
            const int kb = ((KT) + 1) << 6;                                  \
            _Pragma("unroll")                                                \
            for (int it = 0; it < 4; ++it) {                                 \
                RB[it][0] = *(const f32x4*)(pb[it] + kb);                    \
                RB[it][1] = *(const f32x4*)(pb[it] + kb + 4);                \
            }                                                                \
        }                                                                    \
        if ((KT) + 2 < 16) {   /* A for kt+2 (HBM, 2-deep) */                \
            const int kb = ((KT) + 2) << 6;                                  \
            _Pragma("unroll")                                                \
            for (int it = 0; it < 4; ++it) {                                 \
                AREG[it][0] = *(const f32x4*)(pa[it] + kb);                  \
                AREG[it][1] = *(const f32x4*)(pa[it] + kb + 4);              \
            }                                                                \
        }                                                                    \
        __syncthreads();                                                     \
        _Pragma("unroll")                                                    \
        for (int kk = 0; kk < 2; ++kk) {                                     \
            short8 av[4], bv[4];                                             \
            _Pragma("unroll")                                                \
            for (int mi = 0; mi < 4; ++mi) {                                 \
                const int row = (wr << 6) + (mi << 4) + r0;                  \
                const int g   = (kk << 2) + lg;                              \
                av[mi] = *(const short8*)&la[(row << 6) + ((g ^ (row & 7)) << 3)]; \
            }                                                                \
            _Pragma("unroll")                                                \
            for (int ni = 0; ni < 4; ++ni) {                                 \
                const int row = (wc << 6) + (ni << 4) + r0;                  \
                const int g   = (kk << 2) + lg;                              \
                bv[ni] = *(const short8*)&lb[(row << 6) + ((g ^ (row & 7)) << 3)]; \
            }                                                                \
            _Pragma("unroll")                                                \
            for (int mi = 0; mi < 4; ++mi)                                   \
                _Pragma("unroll")                                            \
                for (int ni = 0; ni < 4; ++ni)                               \
                    acc[mi][ni] = __builtin_amdgcn_mfma_f32_16x16x32_bf16(   \
                        av[mi], bv[ni], acc[mi][ni], 0, 0, 0);               \
        }                                                                    \
    }

    for (int t = 0; t < 16; t += 2) {
        GEMM_PHASE(PA, 0, t)        // even tile: LDS buf 0, reg set P
        GEMM_PHASE(QA, 1, t + 1)    // odd tile:  LDS buf 1, reg set Q
    }
#undef GEMM_PHASE

    // ---- epilogue: acc -> LDS (stride 136 shorts) -> coalesced bf16 stores
    __syncthreads();
    short* cs = &lds[0][0][0];   // 128*136 shorts = 34.8 KB, fits
#pragma unroll
    for (int ni = 0; ni < 4; ++ni) {
        const int col = (wc << 6) + (ni << 4) + r0;
        const float bb = bias[o0 + col];
#pragma unroll
        for (int mi = 0; mi < 4; ++mi) {
            const int rb = (wr << 6) + (mi << 4) + (lg << 2);
#pragma unroll
            for (int j = 0; j < 4; ++j)
                cs[(rb + j) * 136 + col] = f2bf(acc[mi][ni][j] + bb);
        }
    }
    __syncthreads();
    const int r16 = tid >> 4, c16 = tid & 15;
    short* cg = (short*)C;
#pragma unroll
    for (int p = 0; p < 8; ++p) {
        const int row = (p << 4) + r16;
        short8 v = *(const short8*)&cs[row * 136 + (c16 << 3)];
        *(short8*)&cg[(size_t)(m0 + row) * OUTF + o0 + (c16 << 3)] = v;
    }
}

// ---------------------------------------------------------------------------
// Scan: u_t = d*u_{t-1} + (1-d)*c_t, segmented (8 segs of 128) with 128-step
// warm-up (d^128 ~ 1.7e-3). cur is bf16. One thread per (b, seg, o).
// ---------------------------------------------------------------------------
template <bool WRITE_OUT>
__global__ __launch_bounds__(256) void scan_kernel(
    const __hip_bfloat16* __restrict__ cur, float* __restrict__ outp,
    float* __restrict__ states, const float* __restrict__ decay) {
    const int gid = blockIdx.x * 256 + threadIdx.x;
    const int o   = gid & 511;
    const int seg = (gid >> 9) & 7;
    const int b   = gid >> 12;

    const float d   = decay[o];
    const float omd = 1.0f - d;
    const __hip_bfloat16* c = cur + (size_t)b * (SEQT * OUTF) + o;
    float* sp = states + (size_t)b * ((SEQT + 1) * OUTF) + o;

    if (seg == 0) sp[0] = 0.0f;

    float u = 0.0f;
    const int t0 = seg << 7;
    const int tw = (seg == 0) ? 0 : (t0 - 128);
    for (int t = tw; t < t0; t += 8) {   // warm-up (no stores)
        float r[8];
#pragma unroll
        for (int j = 0; j < 8; ++j) r[j] = __bfloat162float(c[(size_t)(t + j) * OUTF]);
#pragma unroll
        for (int j = 0; j < 8; ++j) u = fmaf(d, u, omd * r[j]);
    }
    float* op = outp + (size_t)b * (SEQT * OUTF) + o;
    for (int t = t0; t < t0 + 128; t += 8) {
        float r[8];
#pragma unroll
        for (int j = 0; j < 8; ++j) r[j] = __bfloat162float(c[(size_t)(t + j) * OUTF]);
        float uu[8];
#pragma unroll
        for (int j = 0; j < 8; ++j) { u = fmaf(d, u, omd * r[j]); uu[j] = u; }
#pragma unroll
        for (int j = 0; j < 8; ++j) sp[(size_t)(t + 1 + j) * OUTF] = uu[j];
        if (WRITE_OUT) {
#pragma unroll
            for (int j = 0; j < 8; ++j) op[(size_t)(t + j) * OUTF] = uu[j];
        }
    }
}

// outputs[b,t,o] = states[b,t+1,o]  (fallback path only)
__global__ __launch_bounds__(256) void copy_out_kernel(
    float* __restrict__ outp, const float* __restrict__ states) {
    const size_t total = (size_t)MROWS * OUTF / 4;
    size_t i = (size_t)blockIdx.x * blockDim.x + threadIdx.x;
    const size_t stride = (size_t)gridDim.x * blockDim.x;
    for (; i < total; i += stride) {
        const size_t flat = i * 4;
        const size_t o  = flat & 511;
        const size_t bt = flat >> 9;
        const size_t b  = bt >> 10;
        const size_t t  = bt & 1023;
        *(f32x4*)&outp[flat] =
            *(const f32x4*)&states[(b * (SEQT + 1) + t + 1) * OUTF + o];
    }
}

extern "C" void kernel_launch(void* const* d_in, const int* in_sizes, int n_in,
                              void* d_out, int out_size, void* d_ws, size_t ws_size,
                              hipStream_t stream) {
    const float* x     = (const float*)d_in[0];
    const float* w     = (const float*)d_in[1];
    const float* bias  = (const float*)d_in[2];
    const float* decay = (const float*)d_in[3];

    float* outp   = (float*)d_out;
    float* states = outp + (size_t)MROWS * OUTF;   // [B, T+1, OUT] flat

    const size_t cur_bytes = (size_t)MROWS * OUTF * sizeof(__hip_bfloat16);  // 32 MB
    const bool use_ws = (ws_size >= cur_bytes);
    __hip_bfloat16* cur = use_ws ? (__hip_bfloat16*)d_ws : (__hip_bfloat16*)outp;

    gemm_bf16_kernel<<<dim3(1024), dim3(256), 0, stream>>>(x, w, bias, cur);

    if (use_ws) {
        scan_kernel<true><<<dim3(512), dim3(256), 0, stream>>>(cur, outp, states, decay);
    } else {
        scan_kernel<false><<<dim3(512), dim3(256), 0, stream>>>(cur, nullptr, states, decay);
        copy_out_kernel<<<dim3(2048), dim3(256), 0, stream>>>(outp, states);
    }
}

// Round 5
// 106.333 us; speedup vs baseline: 1.3293x; 1.0455x over previous
//
#include <hip/hip_runtime.h>
#include <hip/hip_bf16.h>
#include <stdint.h>

#define BATCH 32
#define SEQT  1024
#define INF   1024
#define OUTF  512
#define MROWS (BATCH * SEQT)   // 32768

typedef __attribute__((ext_vector_type(8))) short short8;
typedef __attribute__((ext_vector_type(4))) float f32x4;

__device__ __forceinline__ short f2bf(float f) {
    return (short)__builtin_bit_cast(unsigned short, __float2bfloat16(f));
}

// async global->LDS DMA, 16B per lane, LDS dest = wave-uniform base + lane*16
__device__ __forceinline__ void gll16(const float* g, float* l) {
    __builtin_amdgcn_global_load_lds(
        (const __attribute__((address_space(1))) unsigned int*)g,
        (__attribute__((address_space(3))) unsigned int*)l, 16, 0, 0);
}

// ---------------------------------------------------------------------------
// GEMM: cur[m,o] = bf16( sum_k X[m,k]*W[o,k] + bias[o] )
// 256x256 tile, BK=32, 512 threads (4x2 waves of 64x128 each).
// fp32 tiles DMA'd to LDS via global_load_lds (linear dest, PRE-SWIZZLED
// global source granule: s' = s ^ (row&7)); fragment read applies the same
// XOR and converts fp32->bf16 in-register (cvt_pk fused by compiler).
// Double-buffered LDS (128 KB), ONE barrier per K-step; gll(next) issued at
// iter top so the DMA has the whole compute phase to land. Grid = 256 = 1/CU.
// ---------------------------------------------------------------------------
__global__ __launch_bounds__(512, 2) void gemm_bf16_kernel(
    const float* __restrict__ X, const float* __restrict__ W,
    const float* __restrict__ bias, __hip_bfloat16* __restrict__ C) {
    __shared__ float lds_f[32768];   // 128 KB: [buf][A 8192 f | B 8192 f]

    const int tid = threadIdx.x;
    const int bid = blockIdx.x;
    // XCD pairing: xcd = bid&7 gets 16 m-tiles x both n-tiles; the two
    // nt-blocks of one mt run concurrently on the same XCD -> X row L2-shared.
    const int xcd = bid & 7;
    const int ii  = bid >> 3;                 // 0..31
    const int mt  = (xcd << 4) + (ii >> 1);   // 0..127
    const int nt  = ii & 1;
    const int m0 = mt << 8;
    const int o0 = nt << 8;

    const int wv   = tid >> 6;
    const int lane = tid & 63;
    const int wr = wv >> 1;       // 0..3  (64-row slab)
    const int wc = wv & 1;        // 0..1  (128-col slab)
    const int r0 = lane & 15;
    const int lg = lane >> 4;     // k-group q = 0..3

    // staging: 2048 granules (16B) per matrix per K-step; 4 rounds x 512 thr.
    // granule g -> row r = g>>3, dest slot g&7; src slot s' = (g&7)^(r&7).
    const float* srcA[4];
    const float* srcB[4];
    int dstf[4];
#pragma unroll
    for (int j = 0; j < 4; ++j) {
        const int g = (j << 9) + tid;
        const int r = g >> 3;
        const int s = (g & 7) ^ (r & 7);
        dstf[j] = g << 2;   // float offset in LDS (linear)
        srcA[j] = X + (size_t)(m0 + r) * INF + (s << 2);
        srcB[j] = W + (size_t)(o0 + r) * INF + (s << 2);
    }

#define STAGE(BUF, KB)                                                       \
    {                                                                        \
        float* ba_ = &lds_f[(BUF) << 14];                                    \
        float* bb_ = ba_ + 8192;                                             \
        _Pragma("unroll")                                                    \
        for (int j = 0; j < 4; ++j) gll16(srcA[j] + (KB), &ba_[dstf[j]]);    \
        _Pragma("unroll")                                                    \
        for (int j = 0; j < 4; ++j) gll16(srcB[j] + (KB), &bb_[dstf[j]]);    \
    }

    f32x4 acc[4][8] = {};

    STAGE(0, 0)
    __syncthreads();   // drain prologue DMA

    for (int kt = 0; kt < 32; ++kt) {
        if (kt < 31) STAGE((kt + 1) & 1, (kt + 1) << 5);
        const float* ba = &lds_f[(kt & 1) << 14];
        const float* bb = ba + 8192;

        short8 av[4], bv[8];
#pragma unroll
        for (int mi = 0; mi < 4; ++mi) {
            const int r  = (wr << 6) + (mi << 4) + r0;
            const int s0 = (lg << 1) ^ (r & 7);
            const f32x4 u0 = *(const f32x4*)&ba[(r << 5) + (s0 << 2)];
            const f32x4 u1 = *(const f32x4*)&ba[(r << 5) + ((s0 ^ 1) << 2)];
            short8 h;
#pragma unroll
            for (int j = 0; j < 4; ++j) { h[j] = f2bf(u0[j]); h[4 + j] = f2bf(u1[j]); }
            av[mi] = h;
        }
#pragma unroll
        for (int ni = 0; ni < 8; ++ni) {
            const int r  = (wc << 7) + (ni << 4) + r0;
            const int s0 = (lg << 1) ^ (r & 7);
            const f32x4 u0 = *(const f32x4*)&bb[(r << 5) + (s0 << 2)];
            const f32x4 u1 = *(const f32x4*)&bb[(r << 5) + ((s0 ^ 1) << 2)];
            short8 h;
#pragma unroll
            for (int j = 0; j < 4; ++j) { h[j] = f2bf(u0[j]); h[4 + j] = f2bf(u1[j]); }
            bv[ni] = h;
        }
#pragma unroll
        for (int mi = 0; mi < 4; ++mi)
#pragma unroll
            for (int ni = 0; ni < 8; ++ni)
                acc[mi][ni] = __builtin_amdgcn_mfma_f32_16x16x32_bf16(
                    av[mi], bv[ni], acc[mi][ni], 0, 0, 0);

        __syncthreads();   // drains this iter's DMA (vmcnt 0) + LDS reads
    }

    // ---- epilogue: 2 passes of 128 rows; acc -> LDS bf16 (stride 264) ->
    //      coalesced short8 global stores.
    short* cs = (short*)lds_f;
#pragma unroll
    for (int pass = 0; pass < 2; ++pass) {
        if ((wr >> 1) == pass) {
#pragma unroll
            for (int ni = 0; ni < 8; ++ni) {
                const int col = (wc << 7) + (ni << 4) + r0;
                const float bbv = bias[o0 + col];
#pragma unroll
                for (int mi = 0; mi < 4; ++mi) {
                    const int lr = ((wr & 1) << 6) + (mi << 4) + (lg << 2);
#pragma unroll
                    for (int j = 0; j < 4; ++j)
                        cs[(lr + j) * 264 + col] = f2bf(acc[mi][ni][j] + bbv);
                }
            }
        }
        __syncthreads();
        short* cg = (short*)C;
#pragma unroll
        for (int sw = 0; sw < 8; ++sw) {
            const int row = (sw << 4) + (tid >> 5);
            const int gr  = tid & 31;
            short8 v = *(const short8*)&cs[row * 264 + (gr << 3)];
            *(short8*)&cg[(size_t)(m0 + (pass << 7) + row) * OUTF + o0 + (gr << 3)] = v;
        }
        if (pass == 0) __syncthreads();
    }
#undef STAGE
}

// ---------------------------------------------------------------------------
// Scan: u_t = d*u_{t-1} + (1-d)*c_t, segmented (8 segs of 128) with 128-step
// warm-up (d^128 ~ 1.7e-3). cur is bf16. One thread per (b, seg, o).
// ---------------------------------------------------------------------------
template <bool WRITE_OUT>
__global__ __launch_bounds__(256) void scan_kernel(
    const __hip_bfloat16* __restrict__ cur, float* __restrict__ outp,
    float* __restrict__ states, const float* __restrict__ decay) {
    const int gid = blockIdx.x * 256 + threadIdx.x;
    const int o   = gid & 511;
    const int seg = (gid >> 9) & 7;
    const int b   = gid >> 12;

    const float d   = decay[o];
    const float omd = 1.0f - d;
    const __hip_bfloat16* c = cur + (size_t)b * (SEQT * OUTF) + o;
    float* sp = states + (size_t)b * ((SEQT + 1) * OUTF) + o;

    if (seg == 0) sp[0] = 0.0f;

    float u = 0.0f;
    const int t0 = seg << 7;
    const int tw = (seg == 0) ? 0 : (t0 - 128);
    for (int t = tw; t < t0; t += 8) {   // warm-up (no stores)
        float r[8];
#pragma unroll
        for (int j = 0; j < 8; ++j) r[j] = __bfloat162float(c[(size_t)(t + j) * OUTF]);
#pragma unroll
        for (int j = 0; j < 8; ++j) u = fmaf(d, u, omd * r[j]);
    }
    float* op = outp + (size_t)b * (SEQT * OUTF) + o;
    for (int t = t0; t < t0 + 128; t += 8) {
        float r[8];
#pragma unroll
        for (int j = 0; j < 8; ++j) r[j] = __bfloat162float(c[(size_t)(t + j) * OUTF]);
        float uu[8];
#pragma unroll
        for (int j = 0; j < 8; ++j) { u = fmaf(d, u, omd * r[j]); uu[j] = u; }
#pragma unroll
        for (int j = 0; j < 8; ++j) sp[(size_t)(t + 1 + j) * OUTF] = uu[j];
        if (WRITE_OUT) {
#pragma unroll
            for (int j = 0; j < 8; ++j) op[(size_t)(t + j) * OUTF] = uu[j];
        }
    }
}

// outputs[b,t,o] = states[b,t+1,o]  (fallback path only)
__global__ __launch_bounds__(256) void copy_out_kernel(
    float* __restrict__ outp, const float* __restrict__ states) {
    const size_t total = (size_t)MROWS * OUTF / 4;
    size_t i = (size_t)blockIdx.x * blockDim.x + threadIdx.x;
    const size_t stride = (size_t)gridDim.x * blockDim.x;
    for (; i < total; i += stride) {
        const size_t flat = i * 4;
        const size_t o  = flat & 511;
        const size_t bt = flat >> 9;
        const size_t b  = bt >> 10;
        const size_t t  = bt & 1023;
        *(f32x4*)&outp[flat] =
            *(const f32x4*)&states[(b * (SEQT + 1) + t + 1) * OUTF + o];
    }
}

extern "C" void kernel_launch(void* const* d_in, const int* in_sizes, int n_in,
                              void* d_out, int out_size, void* d_ws, size_t ws_size,
                              hipStream_t stream) {
    const float* x     = (const float*)d_in[0];
    const float* w     = (const float*)d_in[1];
    const float* bias  = (const float*)d_in[2];
    const float* decay = (const float*)d_in[3];

    float* outp   = (float*)d_out;
    float* states = outp + (size_t)MROWS * OUTF;   // [B, T+1, OUT] flat

    const size_t cur_bytes = (size_t)MROWS * OUTF * sizeof(__hip_bfloat16);  // 32 MB
    const bool use_ws = (ws_size >= cur_bytes);
    __hip_bfloat16* cur = use_ws ? (__hip_bfloat16*)d_ws : (__hip_bfloat16*)outp;

    gemm_bf16_kernel<<<dim3(256), dim3(512), 0, stream>>>(x, w, bias, cur);

    if (use_ws) {
        scan_kernel<true><<<dim3(512), dim3(256), 0, stream>>>(cur, outp, states, decay);
    } else {
        scan_kernel<false><<<dim3(512), dim3(256), 0, stream>>>(cur, nullptr, states, decay);
        copy_out_kernel<<<dim3(2048), dim3(256), 0, stream>>>(outp, states);
    }
}